// Round 2
// baseline (600.003 us; speedup 1.0000x reference)
//
#include <hip/hip_runtime.h>
#include <hip/hip_bf16.h>
#include <stdint.h>

typedef unsigned short ushort_t;
typedef __bf16 bf16x8 __attribute__((ext_vector_type(8)));
typedef float f32x4 __attribute__((ext_vector_type(4)));
typedef ushort_t ushort8v __attribute__((ext_vector_type(8)));

// ---------- helpers ----------

__device__ __forceinline__ ushort_t f2bf(float f) {
  // round-to-nearest-even bf16 (inputs finite normals)
  unsigned int u = __float_as_uint(f);
  u += 0x7FFFu + ((u >> 16) & 1u);
  return (ushort_t)(u >> 16);
}

typedef __attribute__((address_space(1))) void gvoid_t;
typedef __attribute__((address_space(3))) void lvoid_t;

__device__ __forceinline__ void async_cp16(const ushort_t* g, ushort_t* l) {
  // 16B/lane direct global->LDS DMA. LDS dest is wave-uniform base + lane*16.
  __builtin_amdgcn_global_load_lds((gvoid_t*)g, (lvoid_t*)l, 16, 0, 0);
}

__device__ __forceinline__ float dq1(float w, float rs, float s, float z) {
  float q = rintf(w * rs + z);             // RNE, matches jnp.round
  q = fminf(fmaxf(q, 0.0f), 15.0f);
  return (q - z) * s;                      // int in [-15,15] * 2^e : exact in bf16
}

// ---------- fused prep: x fp32->bf16  +  weight qdq->bf16 (grid-stride) ----------

__global__ __launch_bounds__(256) void prep_kernel(
    const float4* __restrict__ x, ushort8v* __restrict__ xb, int xn8,
    const float* __restrict__ w, const float* __restrict__ sc,
    const float* __restrict__ zp, ushort8v* __restrict__ wq, int wn8) {
  const int total = xn8 + wn8;
  const int stride = gridDim.x * 256;
  for (int i = blockIdx.x * 256 + threadIdx.x; i < total; i += stride) {
    if (i < xn8) {
      float4 a = x[2 * i], b = x[2 * i + 1];
      ushort8v o;
      o[0] = f2bf(a.x); o[1] = f2bf(a.y); o[2] = f2bf(a.z); o[3] = f2bf(a.w);
      o[4] = f2bf(b.x); o[5] = f2bf(b.y); o[6] = f2bf(b.z); o[7] = f2bf(b.w);
      xb[i] = o;
    } else {
      int j = i - xn8;
      int base = j * 8;
      int gi = base >> 5;                  // 8-elem span within one 32-group
      float s = sc[gi], z = zp[gi];
      float rs = 1.0f / s;                 // s = 2^e -> exact reciprocal
      const float4* w4 = (const float4*)(w + base);
      float4 a = w4[0], b = w4[1];
      ushort8v o;
      o[0] = f2bf(dq1(a.x, rs, s, z)); o[1] = f2bf(dq1(a.y, rs, s, z));
      o[2] = f2bf(dq1(a.z, rs, s, z)); o[3] = f2bf(dq1(a.w, rs, s, z));
      o[4] = f2bf(dq1(b.x, rs, s, z)); o[5] = f2bf(dq1(b.y, rs, s, z));
      o[6] = f2bf(dq1(b.z, rs, s, z)); o[7] = f2bf(dq1(b.w, rs, s, z));
      wq[j] = o;
    }
  }
}

// ---------- GEMM: C[M,N] = Xbf[M,K] @ Wbf[N,K]^T + bias ----------
// 256x256 tile, BK=64, 8 waves (2M x 4N), per-wave 128x64 via 16x16x32 MFMA.
// Deep-pipeline 4-phase schedule with in-place region-death restaging:
//   fragments are register-cached across phases, so LDS read lifetimes are
//   A s0,s2: P1 only | B s0..s3: P1-P2 | A s1,s3: P3 only.
//   Tile t+2's loads are issued into tile t's buffer as regions die:
//     P2: A(s0,s2)   P3: B(s0..s3)   P4: A(s1,s3)     (8 issues/tile, fixed ring)
//   => every consumed load is 6-7 phases (~1000 cy) old; waits are vmcnt(10)
//   at end of P2 (covers A s1,s3 of current tile) and end of P4 (covers B +
//   A s0,s2 of next tile). Pipeline never drains below 10 outstanding loads.
//   Barriers at phase ends make the per-wave vmcnt guarantees collective.
// LDS swizzle: physical chunk = logical ^ (row&7), applied at the global
// source address (global_load_lds writes linearly) and at ds_read -> 0 bank
// conflicts (verified: SQ_LDS_BANK_CONFLICT == 0).

#define BM 256
#define BN 256
#define BK 64

__device__ __forceinline__ f32x4 mfma16(bf16x8 a, bf16x8 b, f32x4 c) {
  return __builtin_amdgcn_mfma_f32_16x16x32_bf16(a, b, c, 0, 0, 0);
}

template <int MH, int NHB>
__device__ __forceinline__ void mfma_quad(f32x4 acc[2][4][4], const bf16x8 Afr[4][2],
                                          const bf16x8 Bfr[4][2]) {
#pragma unroll
  for (int k = 0; k < 2; ++k)
#pragma unroll
    for (int mt = 0; mt < 4; ++mt)
#pragma unroll
      for (int nt = 0; nt < 2; ++nt)
        acc[MH][mt][NHB * 2 + nt] =
            mfma16(Afr[mt][k], Bfr[NHB * 2 + nt][k], acc[MH][mt][NHB * 2 + nt]);
}

__global__ __launch_bounds__(512, 2) void gemm_bt_bias_kernel(
    const ushort_t* __restrict__ A,   // [M,K] bf16 bits
    const ushort_t* __restrict__ B,   // [N,K] bf16 bits
    const float* __restrict__ bias,   // [N]
    float* __restrict__ C,            // [M,N] fp32
    int M, int N, int K) {
  __shared__ ushort_t sA[2][BM * BK];   // 32 KB per buffer
  __shared__ ushort_t sB[2][BN * BK];   // total 128 KB

  const int tid  = threadIdx.x;
  const int wave = tid >> 6;
  const int lane = tid & 63;
  const int l15 = lane & 15, l4 = lane >> 4;

  // T1: bijective XCD swizzle (grid=512, 512%8==0)
  int wg = blockIdx.x;
  const int nwg = gridDim.x;
  if ((nwg & 7) == 0) wg = (wg & 7) * (nwg >> 3) + (wg >> 3);
  const int nbn = N / BN;
  const int m0 = (wg / nbn) * BM, n0 = (wg % nbn) * BN;
  const int wm = (wave >> 2) * 128, wn = (wave & 3) * 64;

  // staging: stage s covers rows [s*64, s*64+64); chunk = tid, row = tid>>3,
  // physical col-chunk tid&7 holds logical (tid&7)^(row&7)  (pre-swizzled src).
  const int srow = tid >> 3;
  const int scol = ((tid & 7) ^ (srow & 7)) * 8;
  const int ldst = wave * 64 * 8;                  // wave-uniform LDS chunk base

  // fragment read: row = base16 + l15 -> row&7 = l15&7
  const int xa  = l15 & 7;
  const int pc0 = (l4 ^ xa) << 3;                  // kk=0 physical col
  const int pc1 = ((4 + l4) ^ xa) << 3;            // kk=32 physical col
  const int aoff = (wm + l15) * BK;
  const int boff = (wn + l15) * BK;

  f32x4 acc[2][4][4] = {};
  bf16x8 Afr[4][2], Bfr[4][2];

#define STAGE_A(sb, s, kn) \
  async_cp16(A + (size_t)(m0 + (s) * 64 + srow) * K + (kn) + scol, &sA[sb][(s) * 4096 + ldst])
#define STAGE_B(sb, s, kn) \
  async_cp16(B + (size_t)(n0 + (s) * 64 + srow) * K + (kn) + scol, &sB[sb][(s) * 4096 + ldst])
#define LDA(rb, mh, mt, k) \
  (*(const bf16x8*)&sA[rb][aoff + ((mh) * 64 + (mt) * 16) * BK + ((k) ? pc1 : pc0)])
#define LDB(rb, nt, k) \
  (*(const bf16x8*)&sB[rb][boff + (nt) * 16 * BK + ((k) ? pc1 : pc0)])
#define BAR()   __builtin_amdgcn_s_barrier()
#define LGKM0() asm volatile("s_waitcnt lgkmcnt(0)" ::: "memory")
#define VM(n)   asm volatile("s_waitcnt vmcnt(" #n ")" ::: "memory")
#define PRIO(p) __builtin_amdgcn_s_setprio(p)

#define LOAD_A_MH0(rb) \
  _Pragma("unroll") for (int mt = 0; mt < 4; ++mt) { Afr[mt][0] = LDA(rb, 0, mt, 0); Afr[mt][1] = LDA(rb, 0, mt, 1); }
#define LOAD_A_MH1(rb) \
  _Pragma("unroll") for (int mt = 0; mt < 4; ++mt) { Afr[mt][0] = LDA(rb, 1, mt, 0); Afr[mt][1] = LDA(rb, 1, mt, 1); }
#define LOAD_B_LO(rb) \
  _Pragma("unroll") for (int nt = 0; nt < 2; ++nt) { Bfr[nt][0] = LDB(rb, nt, 0); Bfr[nt][1] = LDB(rb, nt, 1); }
#define LOAD_B_HI(rb) \
  _Pragma("unroll") for (int nt = 2; nt < 4; ++nt) { Bfr[nt][0] = LDB(rb, nt, 0); Bfr[nt][1] = LDB(rb, nt, 1); }

  // prologue: stage tiles 0 and 1 in the steady-state ring order
  //   per tile: A s0,A s2 | B s0,B s1,B s2,B s3 | A s1,A s3
  STAGE_A(0, 0, 0);  STAGE_A(0, 2, 0);
  STAGE_B(0, 0, 0);  STAGE_B(0, 1, 0);  STAGE_B(0, 2, 0);  STAGE_B(0, 3, 0);
  STAGE_A(0, 1, 0);  STAGE_A(0, 3, 0);
  STAGE_A(1, 0, BK); STAGE_A(1, 2, BK);
  STAGE_B(1, 0, BK); STAGE_B(1, 1, BK); STAGE_B(1, 2, BK); STAGE_B(1, 3, BK);
  STAGE_A(1, 1, BK); STAGE_A(1, 3, BK);
  VM(10);   // first 6 complete: A(0)s0,s2 + B(0)s0..s3 = exactly P1/P2 needs
  BAR();

  const int nK = K / BK;   // 64 (>= 3 required)
#pragma unroll 2
  for (int t = 0; t < nK - 2; ++t) {
    const int rb = t & 1;
    const int kn2 = (t + 2) * BK;
    // ---- P1: quadrant (mh0, nh0); reads A s0/s2 + B lo ----
    LOAD_A_MH0(rb);
    LOAD_B_LO(rb);
    BAR(); LGKM0();
    PRIO(1); mfma_quad<0, 0>(acc, Afr, Bfr); PRIO(0);
    BAR();
    // ---- P2: quadrant (mh0, nh1); reads B hi; A s0,s2 now dead -> restage t+2 ----
    LOAD_B_HI(rb);
    STAGE_A(rb, 0, kn2); STAGE_A(rb, 2, kn2);
    BAR(); LGKM0();
    PRIO(1); mfma_quad<0, 1>(acc, Afr, Bfr); PRIO(0);
    VM(10);   // guarantees A(t) s1,s3 landed (issued 6 phases ago)
    BAR();
    // ---- P3: quadrant (mh1, nh0); reads A s1/s3; B all dead -> restage t+2 ----
    LOAD_A_MH1(rb);
    STAGE_B(rb, 0, kn2); STAGE_B(rb, 1, kn2); STAGE_B(rb, 2, kn2); STAGE_B(rb, 3, kn2);
    BAR(); LGKM0();
    PRIO(1); mfma_quad<1, 0>(acc, Afr, Bfr); PRIO(0);
    BAR();
    // ---- P4: quadrant (mh1, nh1); regs only; A s1,s3 dead -> restage t+2 ----
    STAGE_A(rb, 1, kn2); STAGE_A(rb, 3, kn2);
    PRIO(1); mfma_quad<1, 1>(acc, Afr, Bfr); PRIO(0);
    VM(10);   // guarantees next tile's A s0,s2 + B s0..s3 landed
    BAR();
  }

  // ---- tile nK-2: no staging; adjusted waits ----
  {
    const int rb = (nK - 2) & 1;
    LOAD_A_MH0(rb);
    LOAD_B_LO(rb);
    BAR(); LGKM0();
    PRIO(1); mfma_quad<0, 0>(acc, Afr, Bfr); PRIO(0);
    BAR();
    LOAD_B_HI(rb);
    BAR(); LGKM0();
    PRIO(1); mfma_quad<0, 1>(acc, Afr, Bfr); PRIO(0);
    VM(8);    // A(nK-2) s1,s3 issued P4 of nK-4; 8 issues after them
    BAR();
    LOAD_A_MH1(rb);
    BAR(); LGKM0();
    PRIO(1); mfma_quad<1, 0>(acc, Afr, Bfr); PRIO(0);
    BAR();
    PRIO(1); mfma_quad<1, 1>(acc, Afr, Bfr); PRIO(0);
    VM(2);    // B(nK-1) landed; A(nK-1) s1,s3 may remain in flight
    BAR();
  }
  // ---- tile nK-1: last ----
  {
    const int rb = (nK - 1) & 1;
    LOAD_A_MH0(rb);
    LOAD_B_LO(rb);
    BAR(); LGKM0();
    PRIO(1); mfma_quad<0, 0>(acc, Afr, Bfr); PRIO(0);
    BAR();
    LOAD_B_HI(rb);
    BAR(); LGKM0();
    PRIO(1); mfma_quad<0, 1>(acc, Afr, Bfr); PRIO(0);
    VM(0);    // drain: A(nK-1) s1,s3 were the final issues
    BAR();
    LOAD_A_MH1(rb);
    BAR(); LGKM0();
    PRIO(1); mfma_quad<1, 0>(acc, Afr, Bfr); PRIO(0);
    BAR();
    PRIO(1); mfma_quad<1, 1>(acc, Afr, Bfr); PRIO(0);
  }

  // epilogue: C/D layout col = lane&15, row = (lane>>4)*4 + reg
  const int ccol = n0 + wn + l15;
  const int crow = m0 + wm + l4 * 4;
#pragma unroll
  for (int nt = 0; nt < 4; ++nt) {
    const float bv = bias[ccol + nt * 16];
#pragma unroll
    for (int mh = 0; mh < 2; ++mh)
#pragma unroll
      for (int mt = 0; mt < 4; ++mt)
#pragma unroll
        for (int r = 0; r < 4; ++r)
          C[(size_t)(crow + mh * 64 + mt * 16 + r) * N + ccol + nt * 16] =
              acc[mh][mt][nt][r] + bv;
  }
}

// ---------- launch ----------

extern "C" void kernel_launch(void* const* d_in, const int* in_sizes, int n_in,
                              void* d_out, int out_size, void* d_ws, size_t ws_size,
                              hipStream_t stream) {
  const float* x    = (const float*)d_in[0];  // [M,K] fp32
  const float* w    = (const float*)d_in[1];  // [N,K] fp32
  const float* bias = (const float*)d_in[2];  // [N]
  const float* sc   = (const float*)d_in[3];  // [N, K/32]
  const float* zp   = (const float*)d_in[4];  // [N, K/32]
  float* out = (float*)d_out;

  const int N = in_sizes[2];       // 4096
  const int K = in_sizes[1] / N;   // 4096
  const int M = in_sizes[0] / K;   // 8192

  ushort_t* xb = (ushort_t*)d_ws;                 // M*K bf16 = 64 MB
  ushort_t* wq = xb + (size_t)M * K;              // N*K bf16 = 32 MB

  int xn8 = (M * K) / 8;
  int wn8 = (N * K) / 8;
  prep_kernel<<<2048, 256, 0, stream>>>((const float4*)x, (ushort8v*)xb, xn8,
                                        w, sc, zp, (ushort8v*)wq, wn8);

  dim3 grid((M / BM) * (N / BN));   // 512 blocks, %8==0 for XCD swizzle
  gemm_bt_bias_kernel<<<grid, 512, 0, stream>>>(xb, wq, bias, out, M, N, K);
}

// Round 3
// 568.569 us; speedup vs baseline: 1.0553x; 1.0553x over previous
//
#include <hip/hip_runtime.h>
#include <hip/hip_bf16.h>
#include <stdint.h>

typedef unsigned short ushort_t;
typedef __bf16 bf16x8 __attribute__((ext_vector_type(8)));
typedef float f32x4 __attribute__((ext_vector_type(4)));
typedef ushort_t ushort8v __attribute__((ext_vector_type(8)));

// ---------- helpers ----------

__device__ __forceinline__ ushort_t f2bf(float f) {
  // round-to-nearest-even bf16 (inputs finite normals)
  unsigned int u = __float_as_uint(f);
  u += 0x7FFFu + ((u >> 16) & 1u);
  return (ushort_t)(u >> 16);
}

typedef __attribute__((address_space(1))) void gvoid_t;
typedef __attribute__((address_space(3))) void lvoid_t;

__device__ __forceinline__ void async_cp16(const ushort_t* g, ushort_t* l) {
  // 16B/lane direct global->LDS DMA. LDS dest is wave-uniform base + lane*16.
  __builtin_amdgcn_global_load_lds((gvoid_t*)g, (lvoid_t*)l, 16, 0, 0);
}

// ---------- prep: x fp32 -> bf16 (16 elems/thread) ----------

__global__ __launch_bounds__(256) void cvt_x_kernel(const float4* __restrict__ x,
                                                    ushort8v* __restrict__ xb, int n16) {
  int i = blockIdx.x * 256 + threadIdx.x;
  if (i >= n16) return;
  float4 a = x[4 * i], b = x[4 * i + 1], c = x[4 * i + 2], d = x[4 * i + 3];
  ushort8v o0, o1;
  o0[0] = f2bf(a.x); o0[1] = f2bf(a.y); o0[2] = f2bf(a.z); o0[3] = f2bf(a.w);
  o0[4] = f2bf(b.x); o0[5] = f2bf(b.y); o0[6] = f2bf(b.z); o0[7] = f2bf(b.w);
  o1[0] = f2bf(c.x); o1[1] = f2bf(c.y); o1[2] = f2bf(c.z); o1[3] = f2bf(c.w);
  o1[4] = f2bf(d.x); o1[5] = f2bf(d.y); o1[6] = f2bf(d.z); o1[7] = f2bf(d.w);
  xb[2 * i] = o0; xb[2 * i + 1] = o1;
}

// ---------- prep: weight quantize->dequant -> bf16 (exact in bf16) ----------

__device__ __forceinline__ float dq1(float w, float rs, float s, float z) {
  float q = rintf(w * rs + z);             // RNE, matches jnp.round
  q = fminf(fmaxf(q, 0.0f), 15.0f);
  return (q - z) * s;                      // int in [-15,15] * 2^e : exact in bf16
}

__global__ __launch_bounds__(256) void dequant_w_kernel(const float* __restrict__ w,
                                                        const float* __restrict__ sc,
                                                        const float* __restrict__ zp,
                                                        ushort8v* __restrict__ wq, int n16) {
  int i = blockIdx.x * 256 + threadIdx.x;
  if (i >= n16) return;
  int base = i * 16;
  int gi = base >> 5;                      // 16-elem span stays within one 32-group
  float s = sc[gi], z = zp[gi];
  float rs = 1.0f / s;                     // s = 2^e -> exact reciprocal
  const float4* w4 = (const float4*)(w + base);
  float4 a = w4[0], b = w4[1], c = w4[2], d = w4[3];
  ushort8v o0, o1;
  o0[0] = f2bf(dq1(a.x, rs, s, z)); o0[1] = f2bf(dq1(a.y, rs, s, z));
  o0[2] = f2bf(dq1(a.z, rs, s, z)); o0[3] = f2bf(dq1(a.w, rs, s, z));
  o0[4] = f2bf(dq1(b.x, rs, s, z)); o0[5] = f2bf(dq1(b.y, rs, s, z));
  o0[6] = f2bf(dq1(b.z, rs, s, z)); o0[7] = f2bf(dq1(b.w, rs, s, z));
  o1[0] = f2bf(dq1(c.x, rs, s, z)); o1[1] = f2bf(dq1(c.y, rs, s, z));
  o1[2] = f2bf(dq1(c.z, rs, s, z)); o1[3] = f2bf(dq1(c.w, rs, s, z));
  o1[4] = f2bf(dq1(d.x, rs, s, z)); o1[5] = f2bf(dq1(d.y, rs, s, z));
  o1[6] = f2bf(dq1(d.z, rs, s, z)); o1[7] = f2bf(dq1(d.w, rs, s, z));
  ushort8v* out8 = (ushort8v*)wq + 2 * i;
  out8[0] = o0; out8[1] = o1;
}

// ---------- GEMM: C[M,N] = Xbf[M,K] @ Wbf[N,K]^T + bias ----------
// 256x256 tile, BK=64, 8 waves (2M x 4N), per-wave 128x64 via 16x16x32 MFMA.
// Barrier-LIGHT schedule: exactly ONE vmcnt(0) + ONE s_barrier per K-tile.
//   per tile t: [vmcnt(0) (t's DMAs, issued a full tile ago -> ~free); s_barrier;
//               issue 8 global_load_lds for t+1 -> other buffer;
//               24 ds_read_b128 + 64 MFMA in ONE scheduling region -- no asm
//               lgkm waits: the compiler inserts counted lgkmcnt(N) before each
//               first use, so ds_reads overlap MFMAs, and the 2 waves/SIMD
//               drift freely covering each other's LDS/matrix-pipe bubbles.
// Safety: reads of buf rb gated by the collective [vmcnt(0); barrier]; DMA into
// sb is safe because every wave's sb-reads were consumed (compiler lgkm-gated)
// before that wave reached the barrier.
// LDS swizzle: physical chunk = logical ^ (row&7), applied at the global source
// address (global_load_lds writes linearly) and at ds_read -> 0 bank conflicts
// (verified on this structure: SQ_LDS_BANK_CONFLICT == 0).

#define BM 256
#define BN 256
#define BK 64

__device__ __forceinline__ f32x4 mfma16(bf16x8 a, bf16x8 b, f32x4 c) {
  return __builtin_amdgcn_mfma_f32_16x16x32_bf16(a, b, c, 0, 0, 0);
}

template <int MH, int NHB>
__device__ __forceinline__ void mfma_quad(f32x4 acc[2][4][4], const bf16x8 Afr[4][2],
                                          const bf16x8 Bfr[4][2]) {
#pragma unroll
  for (int k = 0; k < 2; ++k)
#pragma unroll
    for (int mt = 0; mt < 4; ++mt)
#pragma unroll
      for (int nt = 0; nt < 2; ++nt)
        acc[MH][mt][NHB * 2 + nt] =
            mfma16(Afr[mt][k], Bfr[NHB * 2 + nt][k], acc[MH][mt][NHB * 2 + nt]);
}

__global__ __launch_bounds__(512, 2) void gemm_bt_bias_kernel(
    const ushort_t* __restrict__ A,   // [M,K] bf16 bits
    const ushort_t* __restrict__ B,   // [N,K] bf16 bits
    const float* __restrict__ bias,   // [N]
    float* __restrict__ C,            // [M,N] fp32
    int M, int N, int K) {
  __shared__ ushort_t sA[2][BM * BK];   // 32 KB per buffer
  __shared__ ushort_t sB[2][BN * BK];   // total 128 KB

  const int tid  = threadIdx.x;
  const int wave = tid >> 6;
  const int lane = tid & 63;
  const int l15 = lane & 15, l4 = lane >> 4;

  // T1: bijective XCD swizzle (grid=512, 512%8==0)
  int wg = blockIdx.x;
  const int nwg = gridDim.x;
  if ((nwg & 7) == 0) wg = (wg & 7) * (nwg >> 3) + (wg >> 3);
  const int nbn = N / BN;
  const int m0 = (wg / nbn) * BM, n0 = (wg % nbn) * BN;
  const int wm = (wave >> 2) * 128, wn = (wave & 3) * 64;

  // staging: stage s covers rows [s*64, s*64+64); row = tid>>3 within stage,
  // physical col-chunk tid&7 holds logical (tid&7)^(row&7)  (pre-swizzled src).
  const int srow = tid >> 3;
  const int scol = ((tid & 7) ^ (srow & 7)) * 8;
  const int ldst = wave * 64 * 8;                  // wave-uniform LDS chunk base

  // fragment read: row = base16 + l15 -> row&7 = l15&7
  const int xa  = l15 & 7;
  const int pc0 = (l4 ^ xa) << 3;                  // kk=0 physical col
  const int pc1 = ((4 + l4) ^ xa) << 3;            // kk=32 physical col
  const int aoff = (wm + l15) * BK;
  const int boff = (wn + l15) * BK;

  f32x4 acc[2][4][4] = {};
  bf16x8 Afr[4][2], Bfr[4][2];

#define STAGE_A(sb, s, kn) \
  async_cp16(A + (size_t)(m0 + (s) * 64 + srow) * K + (kn) + scol, &sA[sb][(s) * 4096 + ldst])
#define STAGE_B(sb, s, kn) \
  async_cp16(B + (size_t)(n0 + (s) * 64 + srow) * K + (kn) + scol, &sB[sb][(s) * 4096 + ldst])
#define STAGE_ALL(sb, kn) do { \
  STAGE_A(sb, 0, kn); STAGE_A(sb, 1, kn); STAGE_A(sb, 2, kn); STAGE_A(sb, 3, kn); \
  STAGE_B(sb, 0, kn); STAGE_B(sb, 1, kn); STAGE_B(sb, 2, kn); STAGE_B(sb, 3, kn); \
} while (0)
#define LDA(rb, mh, mt, k) \
  (*(const bf16x8*)&sA[rb][aoff + ((mh) * 64 + (mt) * 16) * BK + ((k) ? pc1 : pc0)])
#define LDB(rb, nt, k) \
  (*(const bf16x8*)&sB[rb][boff + (nt) * 16 * BK + ((k) ? pc1 : pc0)])
#define BAR()   __builtin_amdgcn_s_barrier()
#define VM0()   asm volatile("s_waitcnt vmcnt(0)" ::: "memory")
#define PRIO(p) __builtin_amdgcn_s_setprio(p)

#define LOAD_A_MH0(rb) \
  _Pragma("unroll") for (int mt = 0; mt < 4; ++mt) { Afr[mt][0] = LDA(rb, 0, mt, 0); Afr[mt][1] = LDA(rb, 0, mt, 1); }
#define LOAD_A_MH1(rb) \
  _Pragma("unroll") for (int mt = 0; mt < 4; ++mt) { Afr[mt][0] = LDA(rb, 1, mt, 0); Afr[mt][1] = LDA(rb, 1, mt, 1); }
#define LOAD_B_ALL(rb) \
  _Pragma("unroll") for (int nt = 0; nt < 4; ++nt) { Bfr[nt][0] = LDB(rb, nt, 0); Bfr[nt][1] = LDB(rb, nt, 1); }

  // prologue: stage tile 0 -> buf 0
  STAGE_ALL(0, 0);

  const int nK = K / BK;   // 64
#pragma unroll 2
  for (int t = 0; t < nK - 1; ++t) {
    const int rb = t & 1;
    VM0();                              // tile t's DMAs (issued one tile ago)
    BAR();                              // collective: buf rb ready, buf sb free
    STAGE_ALL(rb ^ 1, (t + 1) * BK);    // prefetch tile t+1
    // ---- free-form interior: compiler-counted lgkm waits, no barriers ----
    LOAD_A_MH0(rb);
    LOAD_B_ALL(rb);
    PRIO(1); mfma_quad<0, 0>(acc, Afr, Bfr); PRIO(0);
    PRIO(1); mfma_quad<0, 1>(acc, Afr, Bfr); PRIO(0);
    LOAD_A_MH1(rb);
    PRIO(1); mfma_quad<1, 0>(acc, Afr, Bfr); PRIO(0);
    PRIO(1); mfma_quad<1, 1>(acc, Afr, Bfr); PRIO(0);
  }
  // ---- last tile: no staging ----
  {
    const int rb = (nK - 1) & 1;
    VM0();
    BAR();
    LOAD_A_MH0(rb);
    LOAD_B_ALL(rb);
    PRIO(1); mfma_quad<0, 0>(acc, Afr, Bfr); PRIO(0);
    PRIO(1); mfma_quad<0, 1>(acc, Afr, Bfr); PRIO(0);
    LOAD_A_MH1(rb);
    PRIO(1); mfma_quad<1, 0>(acc, Afr, Bfr); PRIO(0);
    PRIO(1); mfma_quad<1, 1>(acc, Afr, Bfr); PRIO(0);
  }

  // epilogue: C/D layout col = lane&15, row = (lane>>4)*4 + reg
  const int ccol = n0 + wn + l15;
  const int crow = m0 + wm + l4 * 4;
#pragma unroll
  for (int nt = 0; nt < 4; ++nt) {
    const float bv = bias[ccol + nt * 16];
#pragma unroll
    for (int mh = 0; mh < 2; ++mh)
#pragma unroll
      for (int mt = 0; mt < 4; ++mt)
#pragma unroll
        for (int r = 0; r < 4; ++r)
          C[(size_t)(crow + mh * 64 + mt * 16 + r) * N + ccol + nt * 16] =
              acc[mh][mt][nt][r] + bv;
  }
}

// ---------- launch ----------

extern "C" void kernel_launch(void* const* d_in, const int* in_sizes, int n_in,
                              void* d_out, int out_size, void* d_ws, size_t ws_size,
                              hipStream_t stream) {
  const float* x    = (const float*)d_in[0];  // [M,K] fp32
  const float* w    = (const float*)d_in[1];  // [N,K] fp32
  const float* bias = (const float*)d_in[2];  // [N]
  const float* sc   = (const float*)d_in[3];  // [N, K/32]
  const float* zp   = (const float*)d_in[4];  // [N, K/32]
  float* out = (float*)d_out;

  const int N = in_sizes[2];       // 4096
  const int K = in_sizes[1] / N;   // 4096
  const int M = in_sizes[0] / K;   // 8192

  ushort_t* xb = (ushort_t*)d_ws;                 // M*K bf16 = 64 MB
  ushort_t* wq = xb + (size_t)M * K;              // N*K bf16 = 32 MB

  int xn16 = (M * K) / 16;
  cvt_x_kernel<<<(xn16 + 255) / 256, 256, 0, stream>>>((const float4*)x, (ushort8v*)xb, xn16);

  int wn16 = (N * K) / 16;
  dequant_w_kernel<<<(wn16 + 255) / 256, 256, 0, stream>>>(w, sc, zp, (ushort8v*)wq, wn16);

  dim3 grid((M / BM) * (N / BN));   // 512 blocks, %8==0 for XCD swizzle
  gemm_bt_bias_kernel<<<grid, 512, 0, stream>>>(xb, wq, bias, out, M, N, K);
}

// Round 4
// 555.940 us; speedup vs baseline: 1.0793x; 1.0227x over previous
//
#include <hip/hip_runtime.h>
#include <hip/hip_bf16.h>
#include <stdint.h>

typedef unsigned short ushort_t;
typedef __bf16 bf16x8 __attribute__((ext_vector_type(8)));
typedef float f32x16 __attribute__((ext_vector_type(16)));
typedef ushort_t ushort8v __attribute__((ext_vector_type(8)));

// ---------- helpers ----------

__device__ __forceinline__ ushort_t f2bf(float f) {
  // round-to-nearest-even bf16 (inputs finite normals)
  unsigned int u = __float_as_uint(f);
  u += 0x7FFFu + ((u >> 16) & 1u);
  return (ushort_t)(u >> 16);
}

typedef __attribute__((address_space(1))) void gvoid_t;
typedef __attribute__((address_space(3))) void lvoid_t;

__device__ __forceinline__ void async_cp16(const ushort_t* g, ushort_t* l) {
  // 16B/lane direct global->LDS DMA. LDS dest is wave-uniform base + lane*16.
  __builtin_amdgcn_global_load_lds((gvoid_t*)g, (lvoid_t*)l, 16, 0, 0);
}

// ---------- prep: x fp32 -> bf16 (8 elems/thread) ----------

__global__ __launch_bounds__(256) void cvt_x_kernel(const float4* __restrict__ x,
                                                    ushort8v* __restrict__ xb, int n8) {
  int i = blockIdx.x * 256 + threadIdx.x;
  if (i >= n8) return;
  float4 a = x[2 * i], b = x[2 * i + 1];
  ushort8v o;
  o[0] = f2bf(a.x); o[1] = f2bf(a.y); o[2] = f2bf(a.z); o[3] = f2bf(a.w);
  o[4] = f2bf(b.x); o[5] = f2bf(b.y); o[6] = f2bf(b.z); o[7] = f2bf(b.w);
  xb[i] = o;
}

// ---------- prep: weight quantize->dequant -> bf16 (exact in bf16) ----------

__device__ __forceinline__ float dq1(float w, float rs, float s, float z) {
  float q = rintf(w * rs + z);             // RNE, matches jnp.round
  q = fminf(fmaxf(q, 0.0f), 15.0f);
  return (q - z) * s;                      // int in [-15,15] * 2^e : exact in bf16
}

__global__ __launch_bounds__(256) void dequant_w_kernel(const float* __restrict__ w,
                                                        const float* __restrict__ sc,
                                                        const float* __restrict__ zp,
                                                        ushort8v* __restrict__ wq, int n8) {
  int i = blockIdx.x * 256 + threadIdx.x;
  if (i >= n8) return;
  int base = i * 8;
  int gi = base >> 5;                      // 8-elem span stays within one 32-group
  float s = sc[gi], z = zp[gi];
  float rs = 1.0f / s;                     // s = 2^e -> exact reciprocal
  const float4* w4 = (const float4*)(w + base);
  float4 a = w4[0], b = w4[1];
  ushort8v o;
  o[0] = f2bf(dq1(a.x, rs, s, z)); o[1] = f2bf(dq1(a.y, rs, s, z));
  o[2] = f2bf(dq1(a.z, rs, s, z)); o[3] = f2bf(dq1(a.w, rs, s, z));
  o[4] = f2bf(dq1(b.x, rs, s, z)); o[5] = f2bf(dq1(b.y, rs, s, z));
  o[6] = f2bf(dq1(b.z, rs, s, z)); o[7] = f2bf(dq1(b.w, rs, s, z));
  wq[i] = o;
}

// ---------- GEMM: C[M,N] = Xbf[M,K] @ Wbf[N,K]^T + bias ----------
// 256x256 tile, BK=64, **4 waves**, per-wave 128x128 via 4x4 of 32x32x16 MFMA.
// Rationale (r3 post-mortem): at 8 waves x 128x64, CU LDS traffic/tile (196KB
// reads + 64KB DMA writes ~ 2000-2800 cy) ~= MFMA pipe time (2060 cy) -> LDS is
// co-critical and lockstep waves serialize the two pipes (~37% MfmaUtil across
// 3 schedule variants). 4 waves x 128x128 cuts LDS reads to 128KB/tile (-35%)
// and runs 1 wave/SIMD with an explicit per-wave software pipeline:
//   k-step fragments double-buffered in registers (even/odd), ds_reads issued
//   one 16-MFMA cluster (~515 cy) ahead, exact counted lgkmcnt(8) waits,
//   sched_barrier(0) after each wait (compiler hoists reg-only MFMA past asm
//   waits otherwise). Count audit: boundary issues k0(8)+k1(8) reads; slot_i
//   waits lgkm(8) -> k_{i-1} complete, k_i in flight; slot4 waits lgkm(0).
// DMA: stage tile t+1 right after [vmcnt(0); s_barrier] (VM0 waits DMAs issued
// a full tile ago; BAR makes it collective and guarantees all waves finished
// reading the buffer being overwritten).
// LDS swizzle: physical 8-elem chunk = logical ^ (row&7), pre-applied at the
// global source (DMA writes linearly) and at ds_read -> conflict-free.
// 32x32x16 layouts: A/B row = lane&31, k = kstep*16 + (lane>>5)*8 + [0..8);
// C/D col = lane&31, row = (r&3) + 8*(r>>2) + 4*(lane>>5)  [m74/m101].

#define BM 256
#define BN 256
#define BK 64

__global__ __launch_bounds__(256, 1) void gemm_bt_bias_kernel(
    const ushort_t* __restrict__ A,   // [M,K] bf16 bits
    const ushort_t* __restrict__ B,   // [N,K] bf16 bits
    const float* __restrict__ bias,   // [N]
    float* __restrict__ C,            // [M,N] fp32
    int M, int N, int K) {
  __shared__ ushort_t sA[2][BM * BK];   // 2 x 32 KB
  __shared__ ushort_t sB[2][BN * BK];   // 2 x 32 KB; total 128 KB

  const int tid  = threadIdx.x;
  const int wave = tid >> 6;
  const int lane = tid & 63;
  const int l31 = lane & 31;
  const int kb  = lane >> 5;            // 0/1: which 8-wide k-chunk of K=16

  // T1: bijective XCD swizzle (grid=512, 512%8==0)
  int wg = blockIdx.x;
  const int nwg = gridDim.x;
  if ((nwg & 7) == 0) wg = (wg & 7) * (nwg >> 3) + (wg >> 3);
  const int nbn = N / BN;
  const int m0 = (wg / nbn) * BM, n0 = (wg % nbn) * BN;
  const int wm = (wave >> 1) * 128, wn = (wave & 1) * 128;

  // staging: issue s covers rows [s*32, s*32+32); thread tid -> row tid>>3,
  // physical chunk tid&7 holds logical (tid&7)^(row&7) (pre-swizzled source).
  const int srow = tid >> 3;                       // 0..31
  const int scol = ((tid & 7) ^ (srow & 7)) * 8;
  const int ldst = wave * 512;                     // ushorts; wave-uniform base

  // fragment read: row = base32 + l31 -> row&7 = l31&7
  const int xa   = l31 & 7;
  const int pcs0 = ((0 + kb) ^ xa) << 3;           // kstep 0
  const int pcs1 = ((2 + kb) ^ xa) << 3;           // kstep 1
  const int pcs2 = ((4 + kb) ^ xa) << 3;           // kstep 2
  const int pcs3 = ((6 + kb) ^ xa) << 3;           // kstep 3
  const int aoff = (wm + l31) * BK;
  const int boff = (wn + l31) * BK;

  f32x16 acc[4][4] = {};
  bf16x8 FAe[4], FBe[4], FAo[4], FBo[4];

#define STAGE_A(sb, s, kn) \
  async_cp16(A + (size_t)(m0 + (s) * 32 + srow) * K + (kn) + scol, &sA[sb][(s) * 2048 + ldst])
#define STAGE_B(sb, s, kn) \
  async_cp16(B + (size_t)(n0 + (s) * 32 + srow) * K + (kn) + scol, &sB[sb][(s) * 2048 + ldst])
#define STAGE_ALL(sb, kn) do {                                              \
  STAGE_A(sb, 0, kn); STAGE_A(sb, 1, kn); STAGE_A(sb, 2, kn); STAGE_A(sb, 3, kn); \
  STAGE_A(sb, 4, kn); STAGE_A(sb, 5, kn); STAGE_A(sb, 6, kn); STAGE_A(sb, 7, kn); \
  STAGE_B(sb, 0, kn); STAGE_B(sb, 1, kn); STAGE_B(sb, 2, kn); STAGE_B(sb, 3, kn); \
  STAGE_B(sb, 4, kn); STAGE_B(sb, 5, kn); STAGE_B(sb, 6, kn); STAGE_B(sb, 7, kn); \
} while (0)

#define READ8(rb, PC, FA, FB) do {                                   \
  const ushort_t* pa_ = &sA[rb][aoff + (PC)];                        \
  const ushort_t* pb_ = &sB[rb][boff + (PC)];                        \
  FA[0] = *(const bf16x8*)(pa_);                                     \
  FA[1] = *(const bf16x8*)(pa_ + 2048);                              \
  FA[2] = *(const bf16x8*)(pa_ + 4096);                              \
  FA[3] = *(const bf16x8*)(pa_ + 6144);                              \
  FB[0] = *(const bf16x8*)(pb_);                                     \
  FB[1] = *(const bf16x8*)(pb_ + 2048);                              \
  FB[2] = *(const bf16x8*)(pb_ + 4096);                              \
  FB[3] = *(const bf16x8*)(pb_ + 6144);                              \
} while (0)

#define MFMA16(FA, FB)                                                       \
  _Pragma("unroll") for (int mt = 0; mt < 4; ++mt)                           \
  _Pragma("unroll") for (int nt = 0; nt < 4; ++nt)                           \
      acc[mt][nt] = __builtin_amdgcn_mfma_f32_32x32x16_bf16(FA[mt], FB[nt],  \
                                                            acc[mt][nt], 0, 0, 0);

#define BAR()    __builtin_amdgcn_s_barrier()
#define VM0()    asm volatile("s_waitcnt vmcnt(0)" ::: "memory")
#define LGKM(n)  asm volatile("s_waitcnt lgkmcnt(" #n ")" ::: "memory")
#define SB0()    __builtin_amdgcn_sched_barrier(0)

  // prologue: stage tile 0 -> buf 0
  STAGE_ALL(0, 0);

  const int nK = K / BK;   // 64
#pragma unroll 2
  for (int t = 0; t < nK; ++t) {
    const int rb = t & 1;
    VM0();                               // own DMAs for tile t drained...
    BAR();                               // ...collectively; buf rb^1 free
    READ8(rb, pcs0, FAe, FBe);           // k0 -> even frags
    READ8(rb, pcs1, FAo, FBo);           // k1 -> odd frags
    if (t + 1 < nK) STAGE_ALL(rb ^ 1, (t + 1) * BK);
    LGKM(8); SB0();                      // k0 landed (k1 may be in flight)
    MFMA16(FAe, FBe);
    READ8(rb, pcs2, FAe, FBe);           // k2 -> even (k0 consumed at issue)
    LGKM(8); SB0();                      // k1 landed
    MFMA16(FAo, FBo);
    READ8(rb, pcs3, FAo, FBo);           // k3 -> odd
    LGKM(8); SB0();                      // k2 landed
    MFMA16(FAe, FBe);
    LGKM(0); SB0();                      // k3 landed
    MFMA16(FAo, FBo);
  }

  // epilogue: C/D col = n-col + l31, row = (r&3) + 8*(r>>2) + 4*kb
  const int colbase = n0 + wn + l31;
#pragma unroll
  for (int nt = 0; nt < 4; ++nt) {
    const int col = colbase + nt * 32;
    const float bv = bias[col];
#pragma unroll
    for (int mt = 0; mt < 4; ++mt) {
      const int rowbase = m0 + wm + mt * 32 + 4 * kb;
      const f32x16 v = acc[mt][nt];
#pragma unroll
      for (int r = 0; r < 16; ++r) {
        const int row = rowbase + (r & 3) + 8 * (r >> 2);
        C[(size_t)row * N + col] = v[r] + bv;
      }
    }
  }
}

// ---------- launch ----------

extern "C" void kernel_launch(void* const* d_in, const int* in_sizes, int n_in,
                              void* d_out, int out_size, void* d_ws, size_t ws_size,
                              hipStream_t stream) {
  const float* x    = (const float*)d_in[0];  // [M,K] fp32
  const float* w    = (const float*)d_in[1];  // [N,K] fp32
  const float* bias = (const float*)d_in[2];  // [N]
  const float* sc   = (const float*)d_in[3];  // [N, K/32]
  const float* zp   = (const float*)d_in[4];  // [N, K/32]
  float* out = (float*)d_out;

  const int N = in_sizes[2];       // 4096
  const int K = in_sizes[1] / N;   // 4096
  const int M = in_sizes[0] / K;   // 8192

  ushort_t* xb = (ushort_t*)d_ws;                 // M*K bf16 = 64 MB
  ushort_t* wq = xb + (size_t)M * K;              // N*K bf16 = 32 MB

  int xn8 = (M * K) / 8;
  cvt_x_kernel<<<(xn8 + 255) / 256, 256, 0, stream>>>((const float4*)x, (ushort8v*)xb, xn8);

  int wn8 = (N * K) / 8;
  dequant_w_kernel<<<(wn8 + 255) / 256, 256, 0, stream>>>(w, sc, zp, (ushort8v*)wq, wn8);

  dim3 grid((M / BM) * (N / BN));   // 512 blocks, %8==0 for XCD swizzle
  gemm_bt_bias_kernel<<<grid, 256, 0, stream>>>(xb, wq, bias, out, M, N, K);
}